// Round 4
// baseline (153.543 us; speedup 1.0000x reference)
//
#include <hip/hip_runtime.h>
#include <hip/hip_cooperative_groups.h>

namespace cg = cooperative_groups;

// NALU B=1024, I=512, O=512 — ONE cooperative dispatch, fp16 MFMA 16x16x32.
//   w1 = tanh(w_hat)*sigmoid(m_hat); a = x@w1; s = log(max(|x|,eps))@w1
//   m1 = exp(min(s,20)); out = g1*a + (1-g1)*m1*clip(ms,-1,1)
// s ~ N(-143,11^2) => m1 underflows; guarded exactly: any s > -80 takes a
// cold path computing the true sign-product from wh/mh.
//
// Session history (all measured, fill ~41us is fixed harness poison):
//   R0 two-dispatch (coalesced A+B prep -> lean MFMA main): 68.2us  <- best
//   R1 fused, in-loop A+B build, 1 blk/CU + barrier:        73.8us
//   R2 fused, in-loop A+B build, 2 blk/CU:                  81.0us
//   R3 two-dispatch, B-prep only, in-loop A build:          75.1us
// 3x-confirmed lesson: the MFMA loop must stay LEAN (frag loads + MFMA
// only). Fat loop bodies (logf/cvt per iter) defeat unroll-8 pipelining at
// 2 waves/SIMD regardless of where B comes from. All transforms belong in
// the coalesced streaming prep pass.
//
// R4: attack the last untouched axis — the inter-dispatch gap — WITHOUT
// touching R0's schedule. One cooperative kernel: blocks 0..127 = R0's
// B-prep verbatim, blocks 128..383 = R0's A-prep verbatim, grid.sync()
// (device-scope visibility), then all 512 blocks = R0's main verbatim.
// 512 blocks x 256 thr, launch_bounds(256,2) => exactly co-resident.
//
// Frag layouts (learn_hip-verified): A[m=lane&15][k=(lane>>4)*8+j],
// B[k=(lane>>4)*8+j][n=lane&15], D[m=(lane>>4)*4+reg][n=lane&15].

#define O_N 512
#define I_N 512
#define B_N 1024

typedef _Float16 f16;
typedef _Float16 f16x8 __attribute__((ext_vector_type(8)));
typedef float f32x4 __attribute__((ext_vector_type(4)));

__device__ __forceinline__ float fast_sigmoid(float v) {
    return 1.0f / (1.0f + __expf(-v));
}
__device__ __forceinline__ float fast_tanh(float v) {
    return 1.0f - 2.0f / (1.0f + __expf(2.0f * v));   // exact at both tails
}

__global__ __launch_bounds__(256, 2)
void nalu_coop_kernel(const float* __restrict__ x,
                      const float* __restrict__ wh,
                      const float* __restrict__ mh,
                      const float* __restrict__ g,
                      f16x8* __restrict__ apx,
                      f16x8* __restrict__ apl,
                      f16x8* __restrict__ bp,
                      float* __restrict__ out) {
    __shared__ f16 lt[32][72];          // B-prep transpose tile (blocks 0..127)
    const int tid = threadIdx.x;
    const int blk = blockIdx.x;         // 0..511

    // ================= phase P: prep (R0's two prep halves, verbatim) =====
    if (blk < 128) {
        // ---- B frags: this block handles a 32k x 64n tile of w1
        const int kb = blk >> 3;        // 0..15  (k-tile of 32)
        const int nb = blk & 7;         // 0..7   (n-tile of 64)
        // read phase: row r (32 rows), 8 consecutive n per thread -> coalesced
        const int r  = tid >> 3;
        const int c0 = (tid & 7) * 8;
        const int base = (kb * 32 + r) * O_N + nb * 64 + c0;
        const float4* w4 = (const float4*)(wh + base);
        const float4* m4 = (const float4*)(mh + base);
        const float4 wa = w4[0], wb = w4[1], ma = m4[0], mb = m4[1];
        f16x8 row;
        row[0] = (f16)(fast_tanh(wa.x) * fast_sigmoid(ma.x));
        row[1] = (f16)(fast_tanh(wa.y) * fast_sigmoid(ma.y));
        row[2] = (f16)(fast_tanh(wa.z) * fast_sigmoid(ma.z));
        row[3] = (f16)(fast_tanh(wa.w) * fast_sigmoid(ma.w));
        row[4] = (f16)(fast_tanh(wb.x) * fast_sigmoid(mb.x));
        row[5] = (f16)(fast_tanh(wb.y) * fast_sigmoid(mb.y));
        row[6] = (f16)(fast_tanh(wb.z) * fast_sigmoid(mb.z));
        row[7] = (f16)(fast_tanh(wb.w) * fast_sigmoid(mb.w));
        *(f16x8*)&lt[r][c0] = row;      // one aligned ds_write_b128
        __syncthreads();                // block-uniform branch: safe
        // frag phase: 256 frags, one per thread
        const int fl  = tid & 63;
        const int tnl = tid >> 6;       // 0..3 local n-subtile
        const int nl  = tnl * 16 + (fl & 15);
        const int k0  = (fl >> 4) * 8;
        f16x8 bf;
#pragma unroll
        for (int j = 0; j < 8; ++j) bf[j] = lt[k0 + j][nl];
        const int tn_g = nb * 4 + tnl;  // global n-tile (0..31)
        bp[tn_g * 1024 + kb * 64 + fl] = bf;
    } else if (blk < 384) {
        // ---- A frags: x rows are k-contiguous => direct reads, no transpose
        const int t  = (blk - 128) * 256 + tid;
        const int fl = t & 63;
        const int tk = (t >> 6) & 15;
        const int tm = t >> 10;         // 0..63
        const int m  = tm * 16 + (fl & 15);
        const int k0 = tk * 32 + (fl >> 4) * 8;
        const float4* x4 = (const float4*)(x + m * I_N + k0);
        const float4 q0 = x4[0], q1 = x4[1];
        const float vx[8] = {q0.x, q0.y, q0.z, q0.w, q1.x, q1.y, q1.z, q1.w};
        f16x8 fx, fv;
#pragma unroll
        for (int j = 0; j < 8; ++j) {
            fx[j] = (f16)vx[j];
            fv[j] = (f16)__logf(fmaxf(fabsf(vx[j]), 1e-7f));
        }
        apx[t] = fx;
        apl[t] = fv;
    }

    cg::this_grid().sync();             // device-scope: prep visible to all

    // ================= phase M: main (R0's main kernel, verbatim) =========
    const int lane = tid & 63;
    const int w    = tid >> 6;
    const int b0   = (blk >> 4) * 32 + (w & 1) * 16;
    const int o0   = (blk & 15) * 32 + (w >> 1) * 16;
    const int tm   = b0 >> 4;
    const int tn   = o0 >> 4;

    f32x4 ca = {0.f, 0.f, 0.f, 0.f}, cs = ca;

    const f16x8* pax = apx + tm * 1024 + lane;
    const f16x8* pal = apl + tm * 1024 + lane;
    const f16x8* pbp = bp  + tn * 1024 + lane;

#pragma unroll 8
    for (int tk = 0; tk < 16; ++tk) {
        const f16x8 ax = pax[tk * 64];
        const f16x8 al = pal[tk * 64];
        const f16x8 bf = pbp[tk * 64];
        ca = __builtin_amdgcn_mfma_f32_16x16x32_f16(ax, bf, ca, 0, 0, 0);
        cs = __builtin_amdgcn_mfma_f32_16x16x32_f16(al, bf, cs, 0, 0, 0);
    }

    // epilogue: D[m=(lane>>4)*4+r][n=lane&15]
    const int col = lane & 15;
    const int rq  = (lane >> 4) * 4;
    const int o   = o0 + col;
    const float g1  = fast_sigmoid(g[o]);
    const float omg = 1.0f - g1;
#pragma unroll
    for (int r = 0; r < 4; ++r) {
        const int b = b0 + rq + r;
        const float sv = cs[r];
        const float m1 = __expf(fminf(sv, 20.0f));
        float msv = 1.0f;
        if (sv > -80.0f) {              // cold path (expected never): exact ms
            float p = 1.0f;
            for (int i = 0; i < I_N; ++i) {
                // ws_oi[o][i] = |w1.flat[o*I+i]| = |w1[row=o][col=i]|
                const float wv = fabsf(fast_tanh(wh[o * I_N + i]) *
                                       fast_sigmoid(mh[o * I_N + i]));
                const float xv = x[b * I_N + i];
                const float sg = (xv > 0.f) ? 1.f : ((xv < 0.f) ? -1.f : 0.f);
                p *= sg * wv + (1.0f - wv);
            }
            msv = fminf(fmaxf(p, -1.0f), 1.0f);
        }
        out[b * O_N + o] = g1 * ca[r] + omg * m1 * msv;
    }
}

extern "C" void kernel_launch(void* const* d_in, const int* in_sizes, int n_in,
                              void* d_out, int out_size, void* d_ws, size_t ws_size,
                              hipStream_t stream) {
    const float* x  = (const float*)d_in[0];   // [B, I]
    const float* wh = (const float*)d_in[1];   // [I, O]
    const float* mh = (const float*)d_in[2];   // [I, O]
    const float* g  = (const float*)d_in[3];   // [O]
    float* out = (float*)d_out;                // [B, O] fp32

    char* ws = (char*)d_ws;
    f16x8* apx = (f16x8*)ws;                   // 1 MB  (64*16*64 frags)
    f16x8* apl = (f16x8*)(ws + (1u << 20));    // 1 MB
    f16x8* bp  = (f16x8*)(ws + (2u << 20));    // 512 KB (32*16*64 frags)

    void* args[] = {(void*)&x, (void*)&wh, (void*)&mh, (void*)&g,
                    (void*)&apx, (void*)&apl, (void*)&bp, (void*)&out};
    hipLaunchCooperativeKernel((void*)nalu_coop_kernel, dim3(512), dim3(256),
                               args, 0, stream);
}

// Round 5
// 68.139 us; speedup vs baseline: 2.2534x; 2.2534x over previous
//
#include <hip/hip_runtime.h>

// NALU B=1024, I=512, O=512 — two dispatches, fp16 MFMA 16x16x32.
//   w1 = tanh(w_hat)*sigmoid(m_hat); a = x@w1; s = log(max(|x|,eps))@w1
//   m1 = exp(min(s,20)); out = g1*a + (1-g1)*m1*clip(ms,-1,1)
// s ~ N(-143,11^2) => m1 underflows to 0; guarded exactly: any s > -80
// takes a cold path computing the true sign-product from wh/mh.
//
// Session history (fill ~41us each iter is fixed harness ws-poison):
//   R0 two-dispatch (coalesced prep -> lean MFMA main): 68.2us  <- best
//   R1 fused 16x w1 redundancy:                          73.8us
//   R2 fused 32x w1 redundancy, 2 blk/CU:                81.0us
//   R3 two-dispatch, in-loop A build:                    75.1us
//   R4 cooperative grid.sync fusion:                    153.5us
// R4 counters: whole fused workload = 15.6MB traffic (2.5us of BW);
// grid.sync across 8 XCDs costs ~50us. Lessons: lean MFMA loop only,
// no in-kernel redundancy, no grid sync. R5 = R0 + two micro-fixes:
//   (1) A-prep via LDS transpose: global loads AND stores fully
//       coalesced (R0's A-prep did 16B gathers at 2KB stride);
//       A-prep blocks 256 -> 64.
//   (2) main: XCD-aware swizzle (bid%8 owns 4 consecutive b-tiles) so
//       each A-frag stripe is first-touched by ONE XCD's L2 (~20MB ->
//       ~6MB duplicated L3/HBM fetch).
// Frag layouts (learn_hip-verified): A[m=lane&15][k=(lane>>4)*8+j],
// B[k=(lane>>4)*8+j][n=lane&15], D[m=(lane>>4)*4+reg][n=lane&15].

#define O_N 512
#define I_N 512
#define B_N 1024

typedef _Float16 f16;
typedef _Float16 f16x8 __attribute__((ext_vector_type(8)));
typedef float f32x4 __attribute__((ext_vector_type(4)));

__device__ __forceinline__ float fast_sigmoid(float v) {
    return 1.0f / (1.0f + __expf(-v));
}
__device__ __forceinline__ float fast_tanh(float v) {
    return 1.0f - 2.0f / (1.0f + __expf(2.0f * v));   // exact at both tails
}

// ---- prep: blocks 0..127 = B frags (R0 verbatim), 128..191 = A frags
//      A path: coalesced float4 loads -> transform -> LDS [16][520] f16
//      (row stride 520*2=1040B = 65*16 => 16B-aligned b128, banks offset
//      by 4/row => worst 2-way, free) -> frag gather -> coalesced stores.
__global__ __launch_bounds__(256) void prep_kernel(const float* __restrict__ x,
                                                   const float* __restrict__ wh,
                                                   const float* __restrict__ mh,
                                                   f16x8* __restrict__ apx,
                                                   f16x8* __restrict__ apl,
                                                   f16x8* __restrict__ bp) {
    __shared__ __align__(16) f16 sh[2 * 16 * 520];   // 33280 B; B-path uses 4608 B
    const int tid = threadIdx.x;
    if (blockIdx.x < 128) {
        // ---- B frags: 32k x 64n tile of w1 per block (R0 verbatim)
        f16 (*lt)[72] = (f16 (*)[72])sh;    // 72 = 144B row (16B-mult)
        const int kb = blockIdx.x >> 3;     // 0..15  (k-tile of 32)
        const int nb = blockIdx.x & 7;      // 0..7   (n-tile of 64)
        const int r  = tid >> 3;
        const int c0 = (tid & 7) * 8;
        const int base = (kb * 32 + r) * O_N + nb * 64 + c0;
        const float4* w4 = (const float4*)(wh + base);
        const float4* m4 = (const float4*)(mh + base);
        const float4 wa = w4[0], wb = w4[1], ma = m4[0], mb = m4[1];
        f16x8 row;
        row[0] = (f16)(fast_tanh(wa.x) * fast_sigmoid(ma.x));
        row[1] = (f16)(fast_tanh(wa.y) * fast_sigmoid(ma.y));
        row[2] = (f16)(fast_tanh(wa.z) * fast_sigmoid(ma.z));
        row[3] = (f16)(fast_tanh(wa.w) * fast_sigmoid(ma.w));
        row[4] = (f16)(fast_tanh(wb.x) * fast_sigmoid(mb.x));
        row[5] = (f16)(fast_tanh(wb.y) * fast_sigmoid(mb.y));
        row[6] = (f16)(fast_tanh(wb.z) * fast_sigmoid(mb.z));
        row[7] = (f16)(fast_tanh(wb.w) * fast_sigmoid(mb.w));
        *(f16x8*)&lt[r][c0] = row;          // one aligned ds_write_b128
        __syncthreads();
        const int fl  = tid & 63;
        const int tnl = tid >> 6;           // 0..3 local n-subtile
        const int nl  = tnl * 16 + (fl & 15);
        const int k0  = (fl >> 4) * 8;
        f16x8 bf;
#pragma unroll
        for (int j = 0; j < 8; ++j) bf[j] = lt[k0 + j][nl];
        const int tn_g = nb * 4 + tnl;      // global n-tile (0..31)
        bp[tn_g * 1024 + kb * 64 + fl] = bf;
    } else {
        // ---- A frags: block = tm-stripe (16 rows of x, full k)
        const int blk = blockIdx.x - 128;   // 0..63 = tm
        f16* lxA = sh;                      // [16][520] f16 (x as f16)
        f16* lxB = sh + 16 * 520;           // [16][520] f16 (log|x| as f16)
        // load+transform: 4 passes, wave reads contiguous 2KB per load
#pragma unroll
        for (int p = 0; p < 4; ++p) {
            const int e = p * 2048 + tid * 8;               // 0..8191
            const float4* x4 = (const float4*)(x + blk * 8192 + e);
            const float4 q0 = x4[0], q1 = x4[1];
            const float vx[8] = {q0.x, q0.y, q0.z, q0.w, q1.x, q1.y, q1.z, q1.w};
            const int ml = e >> 9;          // local row 0..15
            const int k  = e & 511;
            f16x8 fx, fv;
#pragma unroll
            for (int j = 0; j < 8; ++j) {
                fx[j] = (f16)vx[j];
                fv[j] = (f16)__logf(fmaxf(fabsf(vx[j]), 1e-7f));
            }
            *(f16x8*)&lxA[ml * 520 + k] = fx;   // aligned ds_write_b128
            *(f16x8*)&lxB[ml * 520 + k] = fv;
        }
        __syncthreads();
        // frag gather: 1024 slots, coalesced 16B stores (consecutive slots)
#pragma unroll
        for (int p = 0; p < 4; ++p) {
            const int s  = p * 256 + tid;   // slot = tk*64 + fl
            const int tk = s >> 6;
            const int fl = s & 63;
            const int ml = fl & 15;
            const int k0 = tk * 32 + (fl >> 4) * 8;
            apx[blk * 1024 + s] = *(const f16x8*)&lxA[ml * 520 + k0];
            apl[blk * 1024 + s] = *(const f16x8*)&lxB[ml * 520 + k0];
        }
    }
}

// ---- main: 512 blocks (1D, XCD-swizzled), 256 thr / 4 waves;
//      block 32b x 32o, wave 16b x 16o. Lean loop: 3 frag loads + 2 MFMA.
__global__ __launch_bounds__(256) void nalu_mfma_kernel(const f16x8* __restrict__ apx,
                                                        const f16x8* __restrict__ apl,
                                                        const f16x8* __restrict__ bp,
                                                        const float* __restrict__ g,
                                                        const float* __restrict__ x,
                                                        const float* __restrict__ wh,
                                                        const float* __restrict__ mh,
                                                        float* __restrict__ out) {
    // XCD swizzle: XCD k (= bid%8) owns b-tiles 4k..4k+3 across all o-tiles,
    // so each 64KB A-frag stripe is resident in exactly one XCD's L2.
    const int bid = blockIdx.x;
    const int swz = (bid & 7) * 64 + (bid >> 3);   // bijective, 512 = 8*64
    const int oT  = swz & 15;                      // 0..15
    const int bT  = swz >> 4;                      // 0..31

    const int lane = threadIdx.x & 63;
    const int w    = threadIdx.x >> 6;
    const int b0   = bT * 32 + (w & 1) * 16;
    const int o0   = oT * 32 + (w >> 1) * 16;
    const int tm   = b0 >> 4;
    const int tn   = o0 >> 4;

    f32x4 ca = {0.f, 0.f, 0.f, 0.f}, cs = ca;

    const f16x8* pax = apx + tm * 1024 + lane;
    const f16x8* pal = apl + tm * 1024 + lane;
    const f16x8* pbp = bp  + tn * 1024 + lane;

#pragma unroll 8
    for (int tk = 0; tk < 16; ++tk) {
        const f16x8 ax = pax[tk * 64];
        const f16x8 al = pal[tk * 64];
        const f16x8 bf = pbp[tk * 64];
        ca = __builtin_amdgcn_mfma_f32_16x16x32_f16(ax, bf, ca, 0, 0, 0);
        cs = __builtin_amdgcn_mfma_f32_16x16x32_f16(al, bf, cs, 0, 0, 0);
    }

    // epilogue: D[m=(lane>>4)*4+r][n=lane&15]
    const int col = lane & 15;
    const int rq  = (lane >> 4) * 4;
    const int o   = o0 + col;
    const float g1  = fast_sigmoid(g[o]);
    const float omg = 1.0f - g1;
#pragma unroll
    for (int r = 0; r < 4; ++r) {
        const int b = b0 + rq + r;
        const float sv = cs[r];
        const float m1 = __expf(fminf(sv, 20.0f));
        float msv = 1.0f;
        if (sv > -80.0f) {                  // cold path (expected never): exact ms
            float p = 1.0f;
            for (int i = 0; i < I_N; ++i) {
                // ws_oi[o][i] = |w1.flat[o*I+i]| = |w1[row=o][col=i]|
                const float wv = fabsf(fast_tanh(wh[o * I_N + i]) *
                                       fast_sigmoid(mh[o * I_N + i]));
                const float xv = x[b * I_N + i];
                const float sg = (xv > 0.f) ? 1.f : ((xv < 0.f) ? -1.f : 0.f);
                p *= sg * wv + (1.0f - wv);
            }
            msv = fminf(fmaxf(p, -1.0f), 1.0f);
        }
        out[b * O_N + o] = g1 * ca[r] + omg * m1 * msv;
    }
}

extern "C" void kernel_launch(void* const* d_in, const int* in_sizes, int n_in,
                              void* d_out, int out_size, void* d_ws, size_t ws_size,
                              hipStream_t stream) {
    const float* x  = (const float*)d_in[0];   // [B, I]
    const float* wh = (const float*)d_in[1];   // [I, O]
    const float* mh = (const float*)d_in[2];   // [I, O]
    const float* g  = (const float*)d_in[3];   // [O]
    float* out = (float*)d_out;                // [B, O] fp32

    char* ws = (char*)d_ws;
    f16x8* apx = (f16x8*)ws;                          // 1 MB  (64*16*64 frags)
    f16x8* apl = (f16x8*)(ws + (1u << 20));           // 1 MB
    f16x8* bp  = (f16x8*)(ws + (2u << 20));           // 512 KB (32*16*64 frags)

    prep_kernel<<<192, 256, 0, stream>>>(x, wh, mh, apx, apl, bp);
    nalu_mfma_kernel<<<512, 256, 0, stream>>>(apx, apl, bp, g, x, wh, mh, out);
}